// Round 1
// baseline (1975.765 us; speedup 1.0000x reference)
//
#include <hip/hip_runtime.h>
#include <hip/hip_bf16.h>
#include <math.h>

using ull = unsigned long long;

// Problem constants
#define ND 4096ull   // n (xd rows)
#define NS 1024ull   // m (s1/s2 rows)
#define DOUT 256ull
#define DIN 768ull
#define NIT 36

// ---- workspace layout (float offsets) ----
constexpr ull O_CXX  = 0;                    // [ND*ND] shared between both divergences
constexpr ull O_CXY  = O_CXX + ND*ND;        // [2][ND*NS]
constexpr ull O_CYX  = O_CXY + 2*ND*NS;      // [2][NS*ND] transposed copies
constexpr ull O_CYY  = O_CYX + 2*ND*NS;      // [2][NS*NS]
constexpr ull O_XD   = O_CYY + 2*NS*NS;      // [ND*DOUT]
constexpr ull O_X1   = O_XD + ND*DOUT;       // [NS*DOUT]
constexpr ull O_X2   = O_X1 + NS*DOUT;       // [NS*DOUT]
constexpr ull O_MT   = O_X2 + NS*DOUT;       // [DOUT*DIN] M transposed
constexpr ull O_ND_  = O_MT + DOUT*DIN;      // [ND] row norms of xd
constexpr ull O_N1   = O_ND_ + ND;           // [NS]
constexpr ull O_N2   = O_N1 + NS;            // [NS]
constexpr ull O_FAB  = O_N2 + NS;            // [2 div][2 buf][ND]
constexpr ull O_GAB  = O_FAB + 4*ND;         // [2][2][NS]
constexpr ull O_FAA  = O_GAB + 4*NS;         // [2][2][ND]
constexpr ull O_GBB  = O_FAA + 4*ND;         // [2][2][NS]
constexpr ull O_FABN = O_GBB + 4*NS;         // [2][ND] final extrapolation
constexpr ull O_GABN = O_FABN + 2*ND;        // [2][NS]
constexpr ull O_FAAN = O_GABN + 2*NS;        // [2][ND]
constexpr ull O_GBBN = O_FAAN + 2*ND;        // [2][NS]
constexpr ull O_EPS  = O_GBBN + 2*NS;        // [2][NIT]
constexpr ull O_DIST = O_EPS + 2*NIT;        // [2]
constexpr ull WS_FLOATS = O_DIST + 2;

__device__ __forceinline__ float wave_max(float v) {
    #pragma unroll
    for (int o = 32; o; o >>= 1) v = fmaxf(v, __shfl_xor(v, o));
    return v;
}
__device__ __forceinline__ float wave_sum(float v) {
    #pragma unroll
    for (int o = 32; o; o >>= 1) v += __shfl_xor(v, o);
    return v;
}

// ---- transpose M [DIN x DOUT] -> Mt [DOUT x DIN] ----
__global__ __launch_bounds__(256)
void transpose_M_k(const float* __restrict__ M, float* __restrict__ Mt)
{
    int idx = blockIdx.x * 256 + threadIdx.x;   // DIN*DOUT total
    int r = idx >> 8;       // row in M (0..767)
    int c = idx & 255;      // col in M (0..255)
    Mt[(size_t)c * DIN + r] = M[idx];
}

// ---- GEMM: P = A[MxK] @ B[NxK]^T ; mode 0: store P; mode 1: cost epilogue ----
__global__ __launch_bounds__(256)
void gemm_abt(const float* __restrict__ A, const float* __restrict__ B,
              float* __restrict__ C, float* __restrict__ CT,
              const float* __restrict__ na, const float* __restrict__ nb,
              int M, int N, int K, int mode)
{
    __shared__ __align__(16) float As[16][68];
    __shared__ __align__(16) float Bs[16][68];
    const int m0 = blockIdx.y * 64, n0 = blockIdx.x * 64;
    const int t = threadIdx.x;
    const int lk = t & 15, lr = t >> 4;   // load mapping
    const int tm = t >> 4, tn = t & 15;   // compute mapping
    float acc[4][4] = {};
    for (int k0 = 0; k0 < K; k0 += 16) {
        #pragma unroll
        for (int r = 0; r < 4; r++) {
            As[lk][lr + r*16] = A[(size_t)(m0 + lr + r*16) * K + (k0 + lk)];
            Bs[lk][lr + r*16] = B[(size_t)(n0 + lr + r*16) * K + (k0 + lk)];
        }
        __syncthreads();
        #pragma unroll
        for (int k = 0; k < 16; k++) {
            const float4 a4 = *(const float4*)&As[k][tm*4];
            const float4 b4 = *(const float4*)&Bs[k][tn*4];
            const float av[4] = {a4.x, a4.y, a4.z, a4.w};
            const float bv[4] = {b4.x, b4.y, b4.z, b4.w};
            #pragma unroll
            for (int i = 0; i < 4; i++)
                #pragma unroll
                for (int j = 0; j < 4; j++)
                    acc[i][j] = fmaf(av[i], bv[j], acc[i][j]);
        }
        __syncthreads();
    }
    if (mode == 0) {
        #pragma unroll
        for (int i = 0; i < 4; i++)
            #pragma unroll
            for (int j = 0; j < 4; j++)
                C[(size_t)(m0 + tm*4 + i) * N + (n0 + tn*4 + j)] = acc[i][j];
    } else {
        #pragma unroll
        for (int i = 0; i < 4; i++) {
            const float nai = na[m0 + tm*4 + i];
            #pragma unroll
            for (int j = 0; j < 4; j++) {
                const float nbj = nb[n0 + tn*4 + j];
                const float sq = nai + nbj - 2.0f * acc[i][j];
                const float c = 0.5f * fmaxf(sq, 0.0f);
                C[(size_t)(m0 + tm*4 + i) * N + (n0 + tn*4 + j)] = c;
                if (CT) CT[(size_t)(n0 + tn*4 + j) * M + (m0 + tm*4 + i)] = c;
            }
        }
    }
}

// ---- row squared-norms (D=256 == blockDim) ----
__global__ __launch_bounds__(256)
void row_norm(const float* __restrict__ x, float* __restrict__ o)
{
    const int i = blockIdx.x;
    const float v = x[(size_t)i * DOUT + threadIdx.x];
    float s = wave_sum(v * v);
    __shared__ float red[4];
    const int wid = threadIdx.x >> 6, lane = threadIdx.x & 63;
    if (lane == 0) red[wid] = s;
    __syncthreads();
    if (threadIdx.x == 0) o[i] = red[0] + red[1] + red[2] + red[3];
}

// ---- bounding-box diameter + eps schedule, one block per divergence ----
__global__ __launch_bounds__(256)
void diam_eps(const float* __restrict__ xd, const float* __restrict__ x1,
              const float* __restrict__ x2, float* __restrict__ ws)
{
    const int d = blockIdx.x;
    const float* y = d ? x2 : x1;
    const int c = threadIdx.x;
    float mx = -3.4e38f, mn = 3.4e38f;
    for (int r = 0; r < (int)ND; r++) {
        const float v = xd[(size_t)r * DOUT + c];
        mx = fmaxf(mx, v); mn = fminf(mn, v);
    }
    for (int r = 0; r < (int)NS; r++) {
        const float v = y[(size_t)r * DOUT + c];
        mx = fmaxf(mx, v); mn = fminf(mn, v);
    }
    const float df = mx - mn;
    float s = wave_sum(df * df);
    __shared__ float red[4];
    __shared__ float diam_sh;
    const int wid = c >> 6, lane = c & 63;
    if (lane == 0) red[wid] = s;
    __syncthreads();
    if (c == 0) diam_sh = sqrtf(red[0] + red[1] + red[2] + red[3]) + 1e-6f;
    __syncthreads();
    const float diam = diam_sh;
    if (c < NIT) {
        const float sc = fmaxf(0.5f, diam * powf(0.8f, (float)c));
        ws[O_EPS + (ull)d * NIT + c] = sc * sc;
    }
}

// ---- per-row stable softmin; row slice cached in registers ----
template<int LEN>
__device__ __forceinline__ void softmin_task(
    const float* __restrict__ Crow, const float* __restrict__ hvec,
    float hconst, float eps, float inv_eps,
    const float* __restrict__ selfv, float* __restrict__ outp,
    int row, int phase, float* red)
{
    constexpr int NK = LEN / 256;
    float v[NK];
    const int tix = threadIdx.x;
    if (hvec) {
        #pragma unroll
        for (int k = 0; k < NK; k++) {
            const int j = tix + k * 256;
            v[k] = fmaf(hvec[j] - Crow[j], inv_eps, hconst);
        }
    } else {
        #pragma unroll
        for (int k = 0; k < NK; k++) {
            const int j = tix + k * 256;
            v[k] = fmaf(-Crow[j], inv_eps, hconst);
        }
    }
    float m = v[0];
    #pragma unroll
    for (int k = 1; k < NK; k++) m = fmaxf(m, v[k]);
    m = wave_max(m);
    const int wid = tix >> 6, lane = tix & 63;
    if (lane == 0) red[wid] = m;
    __syncthreads();
    m = fmaxf(fmaxf(red[0], red[1]), fmaxf(red[2], red[3]));
    float s = 0.0f;
    #pragma unroll
    for (int k = 0; k < NK; k++) s += expf(v[k] - m);
    s = wave_sum(s);
    __syncthreads();   // all reads of red (max) done before reuse
    if (lane == 0) red[wid] = s;
    __syncthreads();
    if (tix == 0) {
        const float tot = red[0] + red[1] + red[2] + red[3];
        float res = -eps * (m + logf(tot));
        if (phase == 1) res = 0.5f * (selfv[row] + res);
        outp[row] = res;
    }
}

// ---- fused Sinkhorn step: 4 softmin tasks x 2 divergences per launch ----
// phase 0: init (h const, direct write to buf0)
// phase 1: Jacobi iteration t (read buf t&1, write buf (t&1)^1, averaged)
// phase 2: final extrapolation at eps_f (read buf0, write *_N arrays)
__global__ __launch_bounds__(256)
void sinkhorn_phase(float* __restrict__ ws, int phase, int t)
{
    constexpr float A_LOG = -8.3177661667193446f;   // -log(4096)
    constexpr float B_LOG = -6.9314718055994531f;   // -log(1024)
    __shared__ float red[4];
    int b = blockIdx.x;
    const int div = (b >= 10240) ? 1 : 0;
    b -= div * 10240;
    const float eps = (phase == 2) ? 0.25f : ws[O_EPS + (ull)div * NIT + t];
    const float inv_eps = 1.0f / eps;
    int rb, wb;
    if (phase == 0) { rb = 0; wb = 0; }
    else { rb = t & 1; wb = rb ^ 1; }   // phase 2 passes t=36 -> rb=0

    float* fab_r = ws + O_FAB + ((ull)div * 2 + rb) * ND;
    float* gab_r = ws + O_GAB + ((ull)div * 2 + rb) * NS;
    float* faa_r = ws + O_FAA + ((ull)div * 2 + rb) * ND;
    float* gbb_r = ws + O_GBB + ((ull)div * 2 + rb) * NS;

    if (b < 4096) {                       // ft -> f_ab (rows of C_xy, len NS)
        const int i = b;
        const float* Crow = ws + O_CXY + (ull)div * ND * NS + (ull)i * NS;
        const float* hvec = phase ? gab_r : nullptr;
        float* outp = (phase == 2) ? (ws + O_FABN + (ull)div * ND)
                                   : (ws + O_FAB + ((ull)div * 2 + wb) * ND);
        softmin_task<1024>(Crow, hvec, B_LOG, eps, inv_eps, fab_r, outp, i, phase, red);
    } else if (b < 5120) {                // gt -> g_ab (rows of C_yx, len ND)
        const int j = b - 4096;
        const float* Crow = ws + O_CYX + (ull)div * ND * NS + (ull)j * ND;
        const float* hvec = phase ? fab_r : nullptr;
        float* outp = (phase == 2) ? (ws + O_GABN + (ull)div * NS)
                                   : (ws + O_GAB + ((ull)div * 2 + wb) * NS);
        softmin_task<4096>(Crow, hvec, A_LOG, eps, inv_eps, gab_r, outp, j, phase, red);
    } else if (b < 9216) {                // f_aa (rows of C_xx, len ND)
        const int i = b - 5120;
        const float* Crow = ws + O_CXX + (ull)i * ND;
        const float* hvec = phase ? faa_r : nullptr;
        float* outp = (phase == 2) ? (ws + O_FAAN + (ull)div * ND)
                                   : (ws + O_FAA + ((ull)div * 2 + wb) * ND);
        softmin_task<4096>(Crow, hvec, A_LOG, eps, inv_eps, faa_r, outp, i, phase, red);
    } else {                              // g_bb (rows of C_yy, len NS)
        const int i = b - 9216;
        const float* Crow = ws + O_CYY + (ull)div * NS * NS + (ull)i * NS;
        const float* hvec = phase ? gbb_r : nullptr;
        float* outp = (phase == 2) ? (ws + O_GBBN + (ull)div * NS)
                                   : (ws + O_GBB + ((ull)div * 2 + wb) * NS);
        softmin_task<1024>(Crow, hvec, B_LOG, eps, inv_eps, gbb_r, outp, i, phase, red);
    }
}

// ---- dist[d] = mean(f_ab_n - f_aa_n) + mean(g_ab_n - g_bb_n) ----
__global__ __launch_bounds__(256)
void reduce_dist(float* __restrict__ ws)
{
    const int d = blockIdx.x;
    const int tix = threadIdx.x;
    float s = 0.0f;
    #pragma unroll
    for (int k = 0; k < 16; k++) {
        const int i = tix + k * 256;
        s += (ws[O_FABN + (ull)d * ND + i] - ws[O_FAAN + (ull)d * ND + i]) * (1.0f / 4096.0f);
    }
    #pragma unroll
    for (int k = 0; k < 4; k++) {
        const int j = tix + k * 256;
        s += (ws[O_GABN + (ull)d * NS + j] - ws[O_GBBN + (ull)d * NS + j]) * (1.0f / 1024.0f);
    }
    s = wave_sum(s);
    __shared__ float red[4];
    const int wid = tix >> 6, lane = tix & 63;
    if (lane == 0) red[wid] = s;
    __syncthreads();
    if (tix == 0) ws[O_DIST + d] = red[0] + red[1] + red[2] + red[3];
}

__global__ void finalize_k(const float* __restrict__ ws, float* __restrict__ out)
{
    const float x = ws[O_DIST + 1] - ws[O_DIST + 0];   // dist2 - dist1
    out[0] = 1.0f / (1.0f + expf(-x));
}

extern "C" void kernel_launch(void* const* d_in, const int* in_sizes, int n_in,
                              void* d_out, int out_size, void* d_ws, size_t ws_size,
                              hipStream_t stream)
{
    if (ws_size < WS_FLOATS * sizeof(float)) return;   // ~150 MB required

    const float* dmat = (const float*)d_in[0];
    const float* s1   = (const float*)d_in[1];
    const float* s2   = (const float*)d_in[2];
    const float* M    = (const float*)d_in[3];
    float* ws  = (float*)d_ws;
    float* out = (float*)d_out;

    float* Mt = ws + O_MT;
    float* xd = ws + O_XD;
    float* x1 = ws + O_X1;
    float* x2 = ws + O_X2;

    transpose_M_k<<<768, 256, 0, stream>>>(M, Mt);
    // projections: X = In @ M  ==  In @ Mt^T
    gemm_abt<<<dim3(4, 64), 256, 0, stream>>>(dmat, Mt, xd, nullptr, nullptr, nullptr, 4096, 256, 768, 0);
    gemm_abt<<<dim3(4, 16), 256, 0, stream>>>(s1,   Mt, x1, nullptr, nullptr, nullptr, 1024, 256, 768, 0);
    gemm_abt<<<dim3(4, 16), 256, 0, stream>>>(s2,   Mt, x2, nullptr, nullptr, nullptr, 1024, 256, 768, 0);
    row_norm<<<4096, 256, 0, stream>>>(xd, ws + O_ND_);
    row_norm<<<1024, 256, 0, stream>>>(x1, ws + O_N1);
    row_norm<<<1024, 256, 0, stream>>>(x2, ws + O_N2);
    // cost matrices
    gemm_abt<<<dim3(64, 64), 256, 0, stream>>>(xd, xd, ws + O_CXX, nullptr, ws + O_ND_, ws + O_ND_, 4096, 4096, 256, 1);
    gemm_abt<<<dim3(16, 64), 256, 0, stream>>>(xd, x1, ws + O_CXY,          ws + O_CYX,          ws + O_ND_, ws + O_N1, 4096, 1024, 256, 1);
    gemm_abt<<<dim3(16, 16), 256, 0, stream>>>(x1, x1, ws + O_CYY,          nullptr,             ws + O_N1,  ws + O_N1, 1024, 1024, 256, 1);
    gemm_abt<<<dim3(16, 64), 256, 0, stream>>>(xd, x2, ws + O_CXY + ND*NS,  ws + O_CYX + ND*NS,  ws + O_ND_, ws + O_N2, 4096, 1024, 256, 1);
    gemm_abt<<<dim3(16, 16), 256, 0, stream>>>(x2, x2, ws + O_CYY + NS*NS,  nullptr,             ws + O_N2,  ws + O_N2, 1024, 1024, 256, 1);
    diam_eps<<<2, 256, 0, stream>>>(xd, x1, x2, ws);
    // Sinkhorn loop
    sinkhorn_phase<<<20480, 256, 0, stream>>>(ws, 0, 0);
    for (int t = 0; t < NIT; t++)
        sinkhorn_phase<<<20480, 256, 0, stream>>>(ws, 1, t);
    sinkhorn_phase<<<20480, 256, 0, stream>>>(ws, 2, 36);
    reduce_dist<<<2, 256, 0, stream>>>(ws);
    finalize_k<<<1, 1, 0, stream>>>(ws, out);
}

// Round 2
// 1516.428 us; speedup vs baseline: 1.3029x; 1.3029x over previous
//
#include <hip/hip_runtime.h>
#include <hip/hip_bf16.h>
#include <math.h>

using ull = unsigned long long;

// Problem constants
#define ND 4096ull   // n (xd rows)
#define NS 1024ull   // m (s1/s2 rows)
#define DOUT 256ull
#define DIN 768ull
#define NIT 36

// ---- workspace layout (float offsets) ----
constexpr ull O_CXX  = 0;                    // [ND*ND] shared between both divergences
constexpr ull O_CXY  = O_CXX + ND*ND;        // [2][ND*NS]
constexpr ull O_CYX  = O_CXY + 2*ND*NS;      // [2][NS*ND] transposed copies
constexpr ull O_CYY  = O_CYX + 2*ND*NS;      // [2][NS*NS]
constexpr ull O_XD   = O_CYY + 2*NS*NS;      // [ND*DOUT]
constexpr ull O_X1   = O_XD + ND*DOUT;       // [NS*DOUT]
constexpr ull O_X2   = O_X1 + NS*DOUT;       // [NS*DOUT]
constexpr ull O_MT   = O_X2 + NS*DOUT;       // [DOUT*DIN] M transposed (dead after GEMMs)
constexpr ull O_ND_  = O_MT + DOUT*DIN;      // [ND] row norms of xd
constexpr ull O_N1   = O_ND_ + ND;           // [NS]
constexpr ull O_N2   = O_N1 + NS;            // [NS]
constexpr ull O_FAB  = O_N2 + NS;            // [2 div][2 buf][ND]
constexpr ull O_GAB  = O_FAB + 4*ND;         // [2][2][NS]
constexpr ull O_FAA  = O_GAB + 4*NS;         // [2][2][ND]
constexpr ull O_GBB  = O_FAA + 4*ND;         // [2][2][NS]
constexpr ull O_FABN = O_GBB + 4*NS;         // [2][ND] final extrapolation
constexpr ull O_GABN = O_FABN + 2*ND;        // [2][NS]
constexpr ull O_FAAN = O_GABN + 2*NS;        // [2][ND]
constexpr ull O_GBBN = O_FAAN + 2*ND;        // [2][NS]
constexpr ull O_EPS  = O_GBBN + 2*NS;        // [2][NIT]
constexpr ull O_DIST = O_EPS + 2*NIT;        // [2]
constexpr ull WS_FLOATS = O_DIST + 2;
// diameter partials reuse the dead Mt region (runs after all GEMMs)
constexpr ull O_PMIN = O_MT;                 // [96*256]
constexpr ull O_PMAX = O_MT + 96*256;        // [96*256]

constexpr float LOG2E = 1.4426950408889634f;
constexpr float LN2   = 0.69314718055994531f;
// a_log*log2e = -log2(4096) = -12 exact; b_log*log2e = -log2(1024) = -10 exact
constexpr float A_LOG2 = -12.0f;
constexpr float B_LOG2 = -10.0f;

__device__ __forceinline__ float wave_max(float v) {
    #pragma unroll
    for (int o = 32; o; o >>= 1) v = fmaxf(v, __shfl_xor(v, o));
    return v;
}
__device__ __forceinline__ float wave_sum(float v) {
    #pragma unroll
    for (int o = 32; o; o >>= 1) v += __shfl_xor(v, o);
    return v;
}

// ---- transpose M [DIN x DOUT] -> Mt [DOUT x DIN] ----
__global__ __launch_bounds__(256)
void transpose_M_k(const float* __restrict__ M, float* __restrict__ Mt)
{
    int idx = blockIdx.x * 256 + threadIdx.x;   // DIN*DOUT total
    int r = idx >> 8;       // row in M (0..767)
    int c = idx & 255;      // col in M (0..255)
    Mt[(size_t)c * DIN + r] = M[idx];
}

// ---- GEMM: P = A[MxK] @ B[NxK]^T ; mode 0: store P; mode 1: cost epilogue ----
__global__ __launch_bounds__(256)
void gemm_abt(const float* __restrict__ A, const float* __restrict__ B,
              float* __restrict__ C, float* __restrict__ CT,
              const float* __restrict__ na, const float* __restrict__ nb,
              int M, int N, int K, int mode)
{
    __shared__ __align__(16) float As[16][68];
    __shared__ __align__(16) float Bs[16][68];
    __shared__ __align__(16) float Ts[64][65];   // CT tile transpose staging
    const int m0 = blockIdx.y * 64, n0 = blockIdx.x * 64;
    const int t = threadIdx.x;
    const int lk = t & 15, lr = t >> 4;   // load mapping
    const int tm = t >> 4, tn = t & 15;   // compute mapping
    float acc[4][4] = {};
    for (int k0 = 0; k0 < K; k0 += 16) {
        #pragma unroll
        for (int r = 0; r < 4; r++) {
            As[lk][lr + r*16] = A[(size_t)(m0 + lr + r*16) * K + (k0 + lk)];
            Bs[lk][lr + r*16] = B[(size_t)(n0 + lr + r*16) * K + (k0 + lk)];
        }
        __syncthreads();
        #pragma unroll
        for (int k = 0; k < 16; k++) {
            const float4 a4 = *(const float4*)&As[k][tm*4];
            const float4 b4 = *(const float4*)&Bs[k][tn*4];
            const float av[4] = {a4.x, a4.y, a4.z, a4.w};
            const float bv[4] = {b4.x, b4.y, b4.z, b4.w};
            #pragma unroll
            for (int i = 0; i < 4; i++)
                #pragma unroll
                for (int j = 0; j < 4; j++)
                    acc[i][j] = fmaf(av[i], bv[j], acc[i][j]);
        }
        __syncthreads();
    }
    if (mode == 0) {
        #pragma unroll
        for (int i = 0; i < 4; i++)
            #pragma unroll
            for (int j = 0; j < 4; j++)
                C[(size_t)(m0 + tm*4 + i) * N + (n0 + tn*4 + j)] = acc[i][j];
    } else {
        #pragma unroll
        for (int i = 0; i < 4; i++) {
            const float nai = na[m0 + tm*4 + i];
            #pragma unroll
            for (int j = 0; j < 4; j++) {
                const float nbj = nb[n0 + tn*4 + j];
                const float sq = nai + nbj - 2.0f * acc[i][j];
                const float c = 0.5f * fmaxf(sq, 0.0f);
                C[(size_t)(m0 + tm*4 + i) * N + (n0 + tn*4 + j)] = c;
                if (CT) Ts[tn*4 + j][tm*4 + i] = c;
            }
        }
        if (CT) {   // coalesced transposed store via LDS
            __syncthreads();
            const int r = t >> 2, c0 = (t & 3) * 16;
            #pragma unroll
            for (int w = 0; w < 4; w++) {
                float4 v = *(const float4*)&Ts[r][c0 + w*4];
                *(float4*)&CT[(size_t)(n0 + r) * M + (m0 + c0 + w*4)] = v;
            }
        }
    }
}

// ---- row squared-norms (D=256 == blockDim) ----
__global__ __launch_bounds__(256)
void row_norm(const float* __restrict__ x, float* __restrict__ o)
{
    const int i = blockIdx.x;
    const float v = x[(size_t)i * DOUT + threadIdx.x];
    float s = wave_sum(v * v);
    __shared__ float red[4];
    const int wid = threadIdx.x >> 6, lane = threadIdx.x & 63;
    if (lane == 0) red[wid] = s;
    __syncthreads();
    if (threadIdx.x == 0) o[i] = red[0] + red[1] + red[2] + red[3];
}

// ---- stage 1: per-column min/max partials (coalesced, 96 blocks) ----
__global__ __launch_bounds__(256)
void colminmax_k(const float* __restrict__ xd, const float* __restrict__ x1,
                 const float* __restrict__ x2, float* __restrict__ ws)
{
    const int b = blockIdx.x, c = threadIdx.x;
    const float* src; int r0;
    if (b < 64)      { src = xd; r0 = b * 64; }
    else if (b < 80) { src = x1; r0 = (b - 64) * 64; }
    else             { src = x2; r0 = (b - 80) * 64; }
    float mn = 3.4e38f, mx = -3.4e38f;
    for (int r = 0; r < 64; r++) {
        const float v = src[(size_t)(r0 + r) * DOUT + c];
        mn = fminf(mn, v); mx = fmaxf(mx, v);
    }
    ws[O_PMIN + (ull)b * 256 + c] = mn;
    ws[O_PMAX + (ull)b * 256 + c] = mx;
}

// ---- stage 2: reduce partials -> diam -> eps schedule (1 block) ----
__global__ __launch_bounds__(256)
void eps_k(float* __restrict__ ws)
{
    const int c = threadIdx.x;
    const float* pmin = ws + O_PMIN;
    const float* pmax = ws + O_PMAX;
    float mnd = 3.4e38f, mxd = -3.4e38f;
    float mn1 = 3.4e38f, mx1 = -3.4e38f;
    float mn2 = 3.4e38f, mx2 = -3.4e38f;
    for (int b = 0;  b < 64; b++) { mnd = fminf(mnd, pmin[b*256+c]); mxd = fmaxf(mxd, pmax[b*256+c]); }
    for (int b = 64; b < 80; b++) { mn1 = fminf(mn1, pmin[b*256+c]); mx1 = fmaxf(mx1, pmax[b*256+c]); }
    for (int b = 80; b < 96; b++) { mn2 = fminf(mn2, pmin[b*256+c]); mx2 = fmaxf(mx2, pmax[b*256+c]); }
    const float d1 = fmaxf(mxd, mx1) - fminf(mnd, mn1);
    const float d2 = fmaxf(mxd, mx2) - fminf(mnd, mn2);
    float s1 = wave_sum(d1 * d1);
    float s2 = wave_sum(d2 * d2);
    __shared__ float r1[4], r2[4];
    const int wid = c >> 6, lane = c & 63;
    if (lane == 0) { r1[wid] = s1; r2[wid] = s2; }
    __syncthreads();
    if (c < 2 * NIT) {
        const int div = c / NIT, tt = c % NIT;
        const float ss = div ? (r2[0]+r2[1]+r2[2]+r2[3]) : (r1[0]+r1[1]+r1[2]+r1[3]);
        const float diam = sqrtf(ss) + 1e-6f;
        const float sc = fmaxf(0.5f, diam * powf(0.8f, (float)tt));
        ws[O_EPS + (ull)div * NIT + tt] = sc * sc;
    }
}

// ---- per-row stable softmin (exp2-scaled), single divergence ----
template<int NK>
__device__ __forceinline__ void softmin_single(
    const float* __restrict__ Crow, const float* __restrict__ hvec,
    float hc2, float eps,
    const float* __restrict__ selfv, float* __restrict__ outp,
    int row, int phase, float* red)
{
    const int tix = threadIdx.x;
    const float ie2 = LOG2E / eps;
    float v[NK];
    if (hvec) {
        #pragma unroll
        for (int k = 0; k < NK; k++) {
            const int j = tix + k * 256;
            v[k] = fmaf(hvec[j] - Crow[j], ie2, hc2);
        }
    } else {
        #pragma unroll
        for (int k = 0; k < NK; k++) {
            const int j = tix + k * 256;
            v[k] = fmaf(-Crow[j], ie2, hc2);
        }
    }
    float m = v[0];
    #pragma unroll
    for (int k = 1; k < NK; k++) m = fmaxf(m, v[k]);
    m = wave_max(m);
    const int wid = tix >> 6, lane = tix & 63;
    if (lane == 0) red[wid] = m;
    __syncthreads();
    m = fmaxf(fmaxf(red[0], red[1]), fmaxf(red[2], red[3]));
    float s = 0.0f;
    #pragma unroll
    for (int k = 0; k < NK; k++) s += exp2f(v[k] - m);
    s = wave_sum(s);
    __syncthreads();
    if (lane == 0) red[wid] = s;
    __syncthreads();
    if (tix == 0) {
        const float tot = red[0] + red[1] + red[2] + red[3];
        float res = -eps * LN2 * (m + log2f(tot));
        if (phase == 1) res = 0.5f * (selfv[row] + res);
        outp[row] = res;
    }
}

// ---- fused f_aa softmin: one C_xx row pass, both divergences ----
__device__ __forceinline__ void softmin_faa(
    const float* __restrict__ Crow,
    const float* __restrict__ h0, const float* __restrict__ h1,
    float eps0, float eps1,
    const float* __restrict__ self0, const float* __restrict__ self1,
    float* __restrict__ out0, float* __restrict__ out1,
    int row, int phase, float* red)
{
    constexpr int NK = 16;
    const int tix = threadIdx.x;
    const float ie0 = LOG2E / eps0;
    const float ie1 = LOG2E / eps1;
    float v0[NK], v1[NK];
    if (phase) {
        #pragma unroll
        for (int k = 0; k < NK; k++) {
            const int j = tix + k * 256;
            const float c = Crow[j];
            v0[k] = fmaf(h0[j] - c, ie0, A_LOG2);
            v1[k] = fmaf(h1[j] - c, ie1, A_LOG2);
        }
    } else {
        #pragma unroll
        for (int k = 0; k < NK; k++) {
            const int j = tix + k * 256;
            const float c = Crow[j];
            v0[k] = fmaf(-c, ie0, A_LOG2);
            v1[k] = fmaf(-c, ie1, A_LOG2);
        }
    }
    float m0 = v0[0], m1 = v1[0];
    #pragma unroll
    for (int k = 1; k < NK; k++) { m0 = fmaxf(m0, v0[k]); m1 = fmaxf(m1, v1[k]); }
    m0 = wave_max(m0); m1 = wave_max(m1);
    const int wid = tix >> 6, lane = tix & 63;
    if (lane == 0) { red[wid] = m0; red[4 + wid] = m1; }
    __syncthreads();
    m0 = fmaxf(fmaxf(red[0], red[1]), fmaxf(red[2], red[3]));
    m1 = fmaxf(fmaxf(red[4], red[5]), fmaxf(red[6], red[7]));
    float s0 = 0.0f, s1 = 0.0f;
    #pragma unroll
    for (int k = 0; k < NK; k++) { s0 += exp2f(v0[k] - m0); s1 += exp2f(v1[k] - m1); }
    s0 = wave_sum(s0); s1 = wave_sum(s1);
    __syncthreads();
    if (lane == 0) { red[wid] = s0; red[4 + wid] = s1; }
    __syncthreads();
    if (tix == 0) {
        const float t0 = red[0] + red[1] + red[2] + red[3];
        const float t1 = red[4] + red[5] + red[6] + red[7];
        float r0 = -eps0 * LN2 * (m0 + log2f(t0));
        float r1 = -eps1 * LN2 * (m1 + log2f(t1));
        if (phase == 1) { r0 = 0.5f * (self0[row] + r0); r1 = 0.5f * (self1[row] + r1); }
        out0[row] = r0; out1[row] = r1;
    }
}

// ---- fused Sinkhorn step ----
// block map (16384 blocks):
//  [0,8192)      ft   (C_xy rows, len 1024), div = b>>12
//  [8192,10240)  gt   (C_yx rows, len 4096), div = (b-8192)>>10
//  [10240,14336) f_aa (C_xx rows, len 4096), BOTH divergences fused
//  [14336,16384) g_bb (C_yy rows, len 1024), div = (b-14336)>>10
__global__ __launch_bounds__(256)
void sinkhorn_phase(float* __restrict__ ws, int phase, int t)
{
    __shared__ float red[8];
    int b = blockIdx.x;
    int rb, wb;
    if (phase == 0) { rb = 0; wb = 0; }
    else { rb = t & 1; wb = rb ^ 1; }   // phase 2 passes t=36 -> rb=0

    if (b < 8192) {                       // ft -> f_ab
        const int div = b >> 12, i = b & 4095;
        const float eps = (phase == 2) ? 0.25f : ws[O_EPS + (ull)div * NIT + t];
        const float* Crow = ws + O_CXY + (ull)div * ND * NS + (ull)i * NS;
        const float* gab_r = ws + O_GAB + ((ull)div * 2 + rb) * NS;
        const float* fab_r = ws + O_FAB + ((ull)div * 2 + rb) * ND;
        float* outp = (phase == 2) ? (ws + O_FABN + (ull)div * ND)
                                   : (ws + O_FAB + ((ull)div * 2 + wb) * ND);
        softmin_single<4>(Crow, phase ? gab_r : nullptr, B_LOG2, eps, fab_r, outp, i, phase, red);
    } else if (b < 10240) {               // gt -> g_ab
        const int q = b - 8192;
        const int div = q >> 10, j = q & 1023;
        const float eps = (phase == 2) ? 0.25f : ws[O_EPS + (ull)div * NIT + t];
        const float* Crow = ws + O_CYX + (ull)div * ND * NS + (ull)j * ND;
        const float* fab_r = ws + O_FAB + ((ull)div * 2 + rb) * ND;
        const float* gab_r = ws + O_GAB + ((ull)div * 2 + rb) * NS;
        float* outp = (phase == 2) ? (ws + O_GABN + (ull)div * NS)
                                   : (ws + O_GAB + ((ull)div * 2 + wb) * NS);
        softmin_single<16>(Crow, phase ? fab_r : nullptr, A_LOG2, eps, gab_r, outp, j, phase, red);
    } else if (b < 14336) {               // f_aa, both divergences
        const int i = b - 10240;
        const float eps0 = (phase == 2) ? 0.25f : ws[O_EPS + t];
        const float eps1 = (phase == 2) ? 0.25f : ws[O_EPS + NIT + t];
        const float* Crow = ws + O_CXX + (ull)i * ND;
        const float* faa_r0 = ws + O_FAA + (ull)rb * ND;
        const float* faa_r1 = ws + O_FAA + (2ull + rb) * ND;
        float* out0 = (phase == 2) ? (ws + O_FAAN)            : (ws + O_FAA + (ull)wb * ND);
        float* out1 = (phase == 2) ? (ws + O_FAAN + ND)       : (ws + O_FAA + (2ull + wb) * ND);
        softmin_faa(Crow, phase ? faa_r0 : nullptr, phase ? faa_r1 : nullptr,
                    eps0, eps1, faa_r0, faa_r1, out0, out1, i, phase, red);
    } else {                              // g_bb
        const int q = b - 14336;
        const int div = q >> 10, i = q & 1023;
        const float eps = (phase == 2) ? 0.25f : ws[O_EPS + (ull)div * NIT + t];
        const float* Crow = ws + O_CYY + (ull)div * NS * NS + (ull)i * NS;
        const float* gbb_r = ws + O_GBB + ((ull)div * 2 + rb) * NS;
        float* outp = (phase == 2) ? (ws + O_GBBN + (ull)div * NS)
                                   : (ws + O_GBB + ((ull)div * 2 + wb) * NS);
        softmin_single<4>(Crow, phase ? gbb_r : nullptr, B_LOG2, eps, gbb_r, outp, i, phase, red);
    }
}

// ---- dist[d] = mean(f_ab_n - f_aa_n) + mean(g_ab_n - g_bb_n) ----
__global__ __launch_bounds__(256)
void reduce_dist(float* __restrict__ ws)
{
    const int d = blockIdx.x;
    const int tix = threadIdx.x;
    float s = 0.0f;
    #pragma unroll
    for (int k = 0; k < 16; k++) {
        const int i = tix + k * 256;
        s += (ws[O_FABN + (ull)d * ND + i] - ws[O_FAAN + (ull)d * ND + i]) * (1.0f / 4096.0f);
    }
    #pragma unroll
    for (int k = 0; k < 4; k++) {
        const int j = tix + k * 256;
        s += (ws[O_GABN + (ull)d * NS + j] - ws[O_GBBN + (ull)d * NS + j]) * (1.0f / 1024.0f);
    }
    s = wave_sum(s);
    __shared__ float red[4];
    const int wid = tix >> 6, lane = tix & 63;
    if (lane == 0) red[wid] = s;
    __syncthreads();
    if (tix == 0) ws[O_DIST + d] = red[0] + red[1] + red[2] + red[3];
}

__global__ void finalize_k(const float* __restrict__ ws, float* __restrict__ out)
{
    const float x = ws[O_DIST + 1] - ws[O_DIST + 0];   // dist2 - dist1
    out[0] = 1.0f / (1.0f + expf(-x));
}

extern "C" void kernel_launch(void* const* d_in, const int* in_sizes, int n_in,
                              void* d_out, int out_size, void* d_ws, size_t ws_size,
                              hipStream_t stream)
{
    if (ws_size < WS_FLOATS * sizeof(float)) return;   // ~150 MB required

    const float* dmat = (const float*)d_in[0];
    const float* s1   = (const float*)d_in[1];
    const float* s2   = (const float*)d_in[2];
    const float* M    = (const float*)d_in[3];
    float* ws  = (float*)d_ws;
    float* out = (float*)d_out;

    float* Mt = ws + O_MT;
    float* xd = ws + O_XD;
    float* x1 = ws + O_X1;
    float* x2 = ws + O_X2;

    transpose_M_k<<<768, 256, 0, stream>>>(M, Mt);
    // projections: X = In @ M  ==  In @ Mt^T
    gemm_abt<<<dim3(4, 64), 256, 0, stream>>>(dmat, Mt, xd, nullptr, nullptr, nullptr, 4096, 256, 768, 0);
    gemm_abt<<<dim3(4, 16), 256, 0, stream>>>(s1,   Mt, x1, nullptr, nullptr, nullptr, 1024, 256, 768, 0);
    gemm_abt<<<dim3(4, 16), 256, 0, stream>>>(s2,   Mt, x2, nullptr, nullptr, nullptr, 1024, 256, 768, 0);
    row_norm<<<4096, 256, 0, stream>>>(xd, ws + O_ND_);
    row_norm<<<1024, 256, 0, stream>>>(x1, ws + O_N1);
    row_norm<<<1024, 256, 0, stream>>>(x2, ws + O_N2);
    // cost matrices
    gemm_abt<<<dim3(64, 64), 256, 0, stream>>>(xd, xd, ws + O_CXX, nullptr, ws + O_ND_, ws + O_ND_, 4096, 4096, 256, 1);
    gemm_abt<<<dim3(16, 64), 256, 0, stream>>>(xd, x1, ws + O_CXY,          ws + O_CYX,          ws + O_ND_, ws + O_N1, 4096, 1024, 256, 1);
    gemm_abt<<<dim3(16, 16), 256, 0, stream>>>(x1, x1, ws + O_CYY,          nullptr,             ws + O_N1,  ws + O_N1, 1024, 1024, 256, 1);
    gemm_abt<<<dim3(16, 64), 256, 0, stream>>>(xd, x2, ws + O_CXY + ND*NS,  ws + O_CYX + ND*NS,  ws + O_ND_, ws + O_N2, 4096, 1024, 256, 1);
    gemm_abt<<<dim3(16, 16), 256, 0, stream>>>(x2, x2, ws + O_CYY + NS*NS,  nullptr,             ws + O_N2,  ws + O_N2, 1024, 1024, 256, 1);
    // diameter + eps schedule (partials overwrite dead Mt region)
    colminmax_k<<<96, 256, 0, stream>>>(xd, x1, x2, ws);
    eps_k<<<1, 256, 0, stream>>>(ws);
    // Sinkhorn loop
    sinkhorn_phase<<<16384, 256, 0, stream>>>(ws, 0, 0);
    for (int t = 0; t < NIT; t++)
        sinkhorn_phase<<<16384, 256, 0, stream>>>(ws, 1, t);
    sinkhorn_phase<<<16384, 256, 0, stream>>>(ws, 2, 36);
    reduce_dist<<<2, 256, 0, stream>>>(ws);
    finalize_k<<<1, 1, 0, stream>>>(ws, out);
}